// Round 2
// baseline (1598.559 us; speedup 1.0000x reference)
//
#include <hip/hip_runtime.h>
#include <hip/hip_bf16.h>

typedef unsigned short u16;
typedef __bf16 bf16x8 __attribute__((ext_vector_type(8)));
typedef float f32x4 __attribute__((ext_vector_type(4)));
typedef unsigned short u16x8 __attribute__((ext_vector_type(8)));

__device__ __forceinline__ u16 f2bf(float f) {
  union { float f; unsigned u; } v; v.f = f;
  unsigned r = (v.u + 0x7FFFu + ((v.u >> 16) & 1u)) >> 16;
  return (u16)r;
}
__device__ __forceinline__ float bf2f(u16 s) {
  union { unsigned u; float f; } v; v.u = ((unsigned)s) << 16;
  return v.f;
}
__device__ __forceinline__ f32x4 zero4() { f32x4 z = {0.f, 0.f, 0.f, 0.f}; return z; }

__device__ __forceinline__ void async16(void* lds, const void* g) {
  __builtin_amdgcn_global_load_lds(
      (__attribute__((address_space(1))) void*)(void*)g,
      (__attribute__((address_space(3))) void*)lds, 16, 0, 0);
}

// ---------------------------------------------------------------------------
// Dtype sniff: decide whether inputs are f32 (mode=1) or bf16 (mode=0).
// Samples low u16 of 256 u32 words of hidden_state. In bf16 data every u16 is
// a sane bf16 (exponent ~[100,150] for N(0,1)); in f32 data the low u16 is
// random mantissa bits (~20% sane). Deterministic -> graph/replay safe.
// ---------------------------------------------------------------------------
__global__ void sniff_dtype(const unsigned* __restrict__ X, int* __restrict__ flag) {
  __shared__ int cnt;
  if (threadIdx.x == 0) cnt = 0;
  __syncthreads();
  unsigned w = X[(size_t)threadIdx.x * 16384 + 1000];
  int e = (int)((w >> 7) & 0xFF);
  if (e >= 100 && e <= 150) atomicAdd(&cnt, 1);
  __syncthreads();
  if (threadIdx.x == 0) flag[0] = (cnt < 192) ? 1 : 0;  // 1 = f32 inputs
}

// ---------------------------------------------------------------------------
// X ingest: 8 elements/thread -> bf16. mode from flag.
// ---------------------------------------------------------------------------
__global__ __launch_bounds__(256) void convert_x(
    const void* __restrict__ X, u16* __restrict__ dst, const int* __restrict__ flag) {
  const int mode = flag[0];
  size_t i8 = ((size_t)blockIdx.x * 256 + threadIdx.x) * 8;
  if (mode) {
    const float4* f = (const float4*)X;
    float4 a = f[i8 / 4], b = f[i8 / 4 + 1];
    u16x8 o;
    o[0] = f2bf(a.x); o[1] = f2bf(a.y); o[2] = f2bf(a.z); o[3] = f2bf(a.w);
    o[4] = f2bf(b.x); o[5] = f2bf(b.y); o[6] = f2bf(b.z); o[7] = f2bf(b.w);
    *(u16x8*)&dst[i8] = o;
  } else {
    *(u16x8*)&dst[i8] = *(const u16x8*)&((const u16*)X)[i8];
  }
}

// ---------------------------------------------------------------------------
// Weight transpose + convert: Wt[n][k] = bf16(W[k][n]), one 2048x2048 matrix.
// ---------------------------------------------------------------------------
__global__ __launch_bounds__(256) void transpose_w(
    const void* __restrict__ src, u16* __restrict__ d, const int* __restrict__ flag)
{
  __shared__ u16 t[64][65];
  const int mode = flag[0];
  int r0 = blockIdx.y * 64, c0 = blockIdx.x * 64;
  int tid = threadIdx.x;
  for (int j = 0; j < 2; ++j) {
    int idx = tid + j * 256;
    int r = idx >> 3, c = (idx & 7) * 8;
    size_t base = (size_t)(r0 + r) * 2048 + c0 + c;
    if (mode) {
      const float4* f = (const float4*)src;
      float4 a = f[base / 4], b = f[base / 4 + 1];
      t[r][c + 0] = f2bf(a.x); t[r][c + 1] = f2bf(a.y);
      t[r][c + 2] = f2bf(a.z); t[r][c + 3] = f2bf(a.w);
      t[r][c + 4] = f2bf(b.x); t[r][c + 5] = f2bf(b.y);
      t[r][c + 6] = f2bf(b.z); t[r][c + 7] = f2bf(b.w);
    } else {
      u16x8 v = *(const u16x8*)&((const u16*)src)[base];
      for (int q = 0; q < 8; ++q) t[r][c + q] = v[q];
    }
  }
  __syncthreads();
  for (int j = 0; j < 2; ++j) {
    int idx = tid + j * 256;
    int c = idx >> 3, r = (idx & 7) * 8;
    u16x8 v;
    for (int q = 0; q < 8; ++q) v[q] = t[r + q][c];
    *(u16x8*)&d[(size_t)(c0 + c) * 2048 + r0 + r] = v;
  }
}

// ---------------------------------------------------------------------------
// V transpose (bf16 internal): Vt[(b*16+h)][d][kv] = V[b*2048+kv][h*128+d]
// ---------------------------------------------------------------------------
__global__ __launch_bounds__(256) void transpose_v(
    const u16* __restrict__ V, u16* __restrict__ Vt)
{
  __shared__ u16 t[64][65];
  int bh = blockIdx.z;
  int b = bh >> 4, h = bh & 15;
  int kv0 = blockIdx.x * 64, d0 = blockIdx.y * 64;
  int tid = threadIdx.x;
  for (int j = 0; j < 2; ++j) {
    int idx = tid + j * 256;
    int r = idx >> 3, c = (idx & 7) * 8;
    u16x8 v = *(const u16x8*)&V[(size_t)(b * 2048 + kv0 + r) * 2048 + h * 128 + d0 + c];
    for (int q = 0; q < 8; ++q) t[r][c + q] = v[q];
  }
  __syncthreads();
  for (int j = 0; j < 2; ++j) {
    int idx = tid + j * 256;
    int c = idx >> 3, r = (idx & 7) * 8;
    u16x8 v;
    for (int q = 0; q < 8; ++q) v[q] = t[r + q][c];
    *(u16x8*)&Vt[((size_t)bh * 128 + d0 + c) * 2048 + kv0 + r] = v;
  }
}

// ---------------------------------------------------------------------------
// RoPE in-place on Q and K (bf16). pos = token % 2048.
// ---------------------------------------------------------------------------
__global__ __launch_bounds__(256) void rope_k(u16* __restrict__ Qp, u16* __restrict__ Kp)
{
  int idx = blockIdx.x * 256 + threadIdx.x;
  u16* X = blockIdx.y ? Kp : Qp;
  int i8 = (idx & 7) * 8;
  int h = (idx >> 3) & 15;
  int tok = idx >> 7;
  int pos = tok & 2047;
  size_t base = (size_t)tok * 2048 + h * 128 + i8;
  u16x8 a = *(const u16x8*)&X[base];
  u16x8 bv = *(const u16x8*)&X[base + 64];
  u16x8 ra, rb;
  for (int j = 0; j < 8; ++j) {
    float fi = (float)(i8 + j);
    float invf = __expf(fi * -0.14391156831212787f);  // ln(10000)/64
    float th = (float)pos * invf;
    float c, s;
    sincosf(th, &s, &c);  // precise: th up to ~2047 rad
    float x1 = bf2f(a[j]), x2 = bf2f(bv[j]);
    ra[j] = f2bf(x1 * c - x2 * s);
    rb[j] = f2bf(x2 * c + x1 * s);
  }
  *(u16x8*)&X[base] = ra;
  *(u16x8*)&X[base + 64] = rb;
}

// ---------------------------------------------------------------------------
// GEMM: C[m][n] = sum_k A[m][k] * Bt[n][k]. A: MxK bf16, Bt: NxK bf16.
// 128x128 tile, BK=32, 4 waves. Epilogue: bf16, or f32 when (dual && flag).
// ---------------------------------------------------------------------------
__global__ __launch_bounds__(256) void gemm_bt(
    const u16* __restrict__ A, const u16* __restrict__ Bt, void* __restrict__ C,
    int M, int N, int K, const int* __restrict__ flag, int dual)
{
  __shared__ __align__(16) u16 As[128 * 32];
  __shared__ __align__(16) u16 Bs[128 * 32];
  const int mode = dual ? flag[0] : 0;
  const int tid = threadIdx.x;
  const int wave = tid >> 6, lane = tid & 63;
  const int quad = lane >> 4, l = lane & 15;
  const int wr = wave >> 1, wc = wave & 1;
  const int m0 = blockIdx.y * 128, n0 = blockIdx.x * 128;

  f32x4 acc[4][4];
  for (int i = 0; i < 4; ++i)
    for (int j = 0; j < 4; ++j) acc[i][j] = zero4();

  for (int kt = 0; kt < K; kt += 32) {
    for (int j = 0; j < 2; ++j) {
      int tf = tid + j * 256;
      int row = tf >> 2, p = tf & 3;
      int g = p ^ ((row >> 1) & 3);
      async16(&As[tf * 8], &A[(size_t)(m0 + row) * K + kt + g * 8]);
      async16(&Bs[tf * 8], &Bt[(size_t)(n0 + row) * K + kt + g * 8]);
    }
    __syncthreads();
    bf16x8 af[4], bfr[4];
    for (int mt = 0; mt < 4; ++mt) {
      int row = wr * 64 + mt * 16 + l;
      int g = quad ^ ((row >> 1) & 3);
      af[mt] = *(const bf16x8*)&As[row * 32 + g * 8];
    }
    for (int nt = 0; nt < 4; ++nt) {
      int row = wc * 64 + nt * 16 + l;
      int g = quad ^ ((row >> 1) & 3);
      bfr[nt] = *(const bf16x8*)&Bs[row * 32 + g * 8];
    }
    for (int mt = 0; mt < 4; ++mt)
      for (int nt = 0; nt < 4; ++nt)
        acc[mt][nt] = __builtin_amdgcn_mfma_f32_16x16x32_bf16(af[mt], bfr[nt], acc[mt][nt], 0, 0, 0);
    __syncthreads();
  }
  for (int mt = 0; mt < 4; ++mt)
    for (int nt = 0; nt < 4; ++nt)
      for (int r = 0; r < 4; ++r) {
        int m = m0 + wr * 64 + mt * 16 + quad * 4 + r;
        int n = n0 + wc * 64 + nt * 16 + l;
        if (mode) ((float*)C)[(size_t)m * N + n] = acc[mt][nt][r];
        else      ((u16*)C)[(size_t)m * N + n] = f2bf(acc[mt][nt][r]);
      }
}

// ---------------------------------------------------------------------------
// Flash attention, causal. grid (32 q-tiles [reversed], 16 h, 2 b).
// BQ=64, BKV=64, 4 waves x 16 q-rows. Online softmax per quad.
// ---------------------------------------------------------------------------
__global__ __launch_bounds__(256) void flash_k(
    const u16* __restrict__ Q, const u16* __restrict__ K,
    const u16* __restrict__ Vt, u16* __restrict__ O)
{
  __shared__ __align__(16) u16 Qs[64 * 128];
  __shared__ __align__(16) u16 Ks[64 * 128];
  __shared__ __align__(16) u16 Vs[128 * 64];
  __shared__ __align__(16) u16 Ps[4][16 * 64];

  const int tid = threadIdx.x;
  const int wave = tid >> 6, lane = tid & 63;
  const int quad = lane >> 4, l = lane & 15;
  const int qt = (int)gridDim.x - 1 - (int)blockIdx.x;
  const int h = blockIdx.y, b = blockIdx.z;

  const size_t qoff = ((size_t)(b * 2048 + qt * 64)) * 2048 + h * 128;
  for (int j = 0; j < 4; ++j) {
    int tf = tid + j * 256;
    int row = tf >> 4, p = tf & 15;
    int g = p ^ (row & 7);
    async16(&Qs[tf * 8], &Q[qoff + (size_t)row * 2048 + g * 8]);
  }

  f32x4 Oacc[8];
  for (int i = 0; i < 8; ++i) Oacc[i] = zero4();
  float mi[4] = {-3e38f, -3e38f, -3e38f, -3e38f};
  float li[4] = {0.f, 0.f, 0.f, 0.f};

  const size_t kbase = ((size_t)b * 2048) * 2048 + h * 128;
  const size_t vbase = ((size_t)(b * 16 + h)) * 128 * 2048;

  for (int kt = 0; kt <= qt; ++kt) {
    for (int j = 0; j < 4; ++j) {
      int tf = tid + j * 256;
      int row = tf >> 4, p = tf & 15;
      int g = p ^ (row & 7);
      async16(&Ks[tf * 8], &K[kbase + (size_t)(kt * 64 + row) * 2048 + g * 8]);
    }
    for (int j = 0; j < 4; ++j) {
      int tf = tid + j * 256;
      int row = tf >> 3, p = tf & 7;
      int g = p ^ (row & 7);
      async16(&Vs[tf * 8], &Vt[vbase + (size_t)row * 2048 + kt * 64 + g * 8]);
    }
    __syncthreads();

    f32x4 S[4];
    for (int nt = 0; nt < 4; ++nt) S[nt] = zero4();
    for (int ks = 0; ks < 4; ++ks) {
      int g = ks * 4 + quad;
      bf16x8 aq = *(const bf16x8*)&Qs[(wave * 16 + l) * 128 + (g ^ (l & 7)) * 8];
      for (int nt = 0; nt < 4; ++nt) {
        bf16x8 bk = *(const bf16x8*)&Ks[(nt * 16 + l) * 128 + (g ^ (l & 7)) * 8];
        S[nt] = __builtin_amdgcn_mfma_f32_16x16x32_bf16(aq, bk, S[nt], 0, 0, 0);
      }
    }

    const bool dg = (kt == qt);
    float Pv[4][4];
    float rm[4] = {-3e38f, -3e38f, -3e38f, -3e38f};
    for (int nt = 0; nt < 4; ++nt)
      for (int r = 0; r < 4; ++r) {
        float s = S[nt][r] * 0.08838834764831845f;  // 1/sqrt(128)
        if (dg && (nt * 16 + l > wave * 16 + quad * 4 + r)) s = -3e38f;
        Pv[nt][r] = s;
        rm[r] = fmaxf(rm[r], s);
      }
    for (int r = 0; r < 4; ++r)
      for (int off = 1; off < 16; off <<= 1)
        rm[r] = fmaxf(rm[r], __shfl_xor(rm[r], off));
    float al[4], rs[4];
    for (int r = 0; r < 4; ++r) {
      float mn = fmaxf(mi[r], rm[r]);
      al[r] = __expf(mi[r] - mn);
      mi[r] = mn;
      rs[r] = 0.f;
    }
    for (int nt = 0; nt < 4; ++nt)
      for (int r = 0; r < 4; ++r) {
        float p = __expf(Pv[nt][r] - mi[r]);
        Pv[nt][r] = p;
        rs[r] += p;
      }
    for (int r = 0; r < 4; ++r) {
      for (int off = 1; off < 16; off <<= 1)
        rs[r] += __shfl_xor(rs[r], off);
      li[r] = li[r] * al[r] + rs[r];
    }
    for (int nt = 0; nt < 4; ++nt) {
      int gc = nt * 2 + (l >> 3);
      for (int r = 0; r < 4; ++r) {
        int row = quad * 4 + r;
        Ps[wave][row * 64 + ((gc ^ (row & 7)) * 8) + (l & 7)] = f2bf(Pv[nt][r]);
      }
    }
    for (int d = 0; d < 8; ++d)
      for (int r = 0; r < 4; ++r) Oacc[d][r] *= al[r];
    for (int ks = 0; ks < 2; ++ks) {
      int g = ks * 4 + quad;
      bf16x8 ap = *(const bf16x8*)&Ps[wave][l * 64 + (g ^ (l & 7)) * 8];
      for (int d = 0; d < 8; ++d) {
        bf16x8 bv = *(const bf16x8*)&Vs[(d * 16 + l) * 64 + (g ^ (l & 7)) * 8];
        Oacc[d] = __builtin_amdgcn_mfma_f32_16x16x32_bf16(ap, bv, Oacc[d], 0, 0, 0);
      }
    }
    __syncthreads();
  }

  float inv[4];
  for (int r = 0; r < 4; ++r) inv[r] = 1.f / li[r];
  size_t obase = ((size_t)(b * 2048 + qt * 64 + wave * 16)) * 2048 + h * 128;
  for (int d = 0; d < 8; ++d)
    for (int r = 0; r < 4; ++r)
      O[obase + (size_t)(quad * 4 + r) * 2048 + d * 16 + l] = f2bf(Oacc[d][r] * inv[r]);
}

// ---------------------------------------------------------------------------
extern "C" void kernel_launch(void* const* d_in, const int* in_sizes, int n_in,
                              void* d_out, int out_size, void* d_ws, size_t ws_size,
                              hipStream_t stream) {
  const void* X  = d_in[0];   // hidden_state (4096 x 2048), f32 or bf16
  const void* Wq = d_in[3];
  const void* Wk = d_in[4];
  const void* Wv = d_in[5];
  const void* Wo = d_in[6];

  u16* base = (u16*)d_ws;
  int* flag = (int*)d_ws;              // 256-byte header
  const size_t TOK = 4096, DM = 2048;
  u16* Xbf = base + 128;               // 8M u16 (also reused as Vt later)
  u16* Qw  = Xbf + TOK * DM;
  u16* Kw  = Qw + TOK * DM;
  u16* Vw  = Kw + TOK * DM;            // V, then attention output
  u16* WTb = Vw + TOK * DM;            // 4M u16, reused per weight
  u16* Vtw = Xbf;                      // X dead after QKV gemms

  sniff_dtype<<<1, 256, 0, stream>>>((const unsigned*)X, flag);
  convert_x<<<4096, 256, 0, stream>>>(X, Xbf, flag);

  transpose_w<<<dim3(32, 32), 256, 0, stream>>>(Wq, WTb, flag);
  gemm_bt<<<dim3(16, 32), 256, 0, stream>>>(Xbf, WTb, Qw, 4096, 2048, 2048, flag, 0);
  transpose_w<<<dim3(32, 32), 256, 0, stream>>>(Wk, WTb, flag);
  gemm_bt<<<dim3(16, 32), 256, 0, stream>>>(Xbf, WTb, Kw, 4096, 2048, 2048, flag, 0);
  transpose_w<<<dim3(32, 32), 256, 0, stream>>>(Wv, WTb, flag);
  gemm_bt<<<dim3(16, 32), 256, 0, stream>>>(Xbf, WTb, Vw, 4096, 2048, 2048, flag, 0);

  rope_k<<<dim3(2048, 2), 256, 0, stream>>>(Qw, Kw);
  transpose_v<<<dim3(32, 2, 32), 256, 0, stream>>>(Vw, Vtw);
  flash_k<<<dim3(32, 16, 2), 256, 0, stream>>>(Qw, Kw, Vtw, Vw);

  transpose_w<<<dim3(32, 32), 256, 0, stream>>>(Wo, WTb, flag);
  gemm_bt<<<dim3(16, 32), 256, 0, stream>>>(Vw, WTb, d_out, 4096, 2048, 2048, flag, 1);
}

// Round 5
// 1577.484 us; speedup vs baseline: 1.0134x; 1.0134x over previous
//
#include <hip/hip_runtime.h>
#include <hip/hip_bf16.h>

typedef unsigned short u16;
typedef __bf16 bf16x8 __attribute__((ext_vector_type(8)));
typedef float f32x4 __attribute__((ext_vector_type(4)));
typedef unsigned short u16x8 __attribute__((ext_vector_type(8)));

__device__ __forceinline__ u16 f2bf(float f) {
  union { float f; unsigned u; } v; v.f = f;
  unsigned r = (v.u + 0x7FFFu + ((v.u >> 16) & 1u)) >> 16;
  return (u16)r;
}
__device__ __forceinline__ float bf2f(u16 s) {
  union { unsigned u; float f; } v; v.u = ((unsigned)s) << 16;
  return v.f;
}
__device__ __forceinline__ f32x4 zero4() { f32x4 z = {0.f, 0.f, 0.f, 0.f}; return z; }

__device__ __forceinline__ void async16(void* lds, const void* g) {
  __builtin_amdgcn_global_load_lds(
      (__attribute__((address_space(1))) void*)(void*)g,
      (__attribute__((address_space(3))) void*)lds, 16, 0, 0);
}

// ---------------------------------------------------------------------------
// Dtype sniff: 1 = f32 inputs, 0 = bf16 inputs. Deterministic.
// ---------------------------------------------------------------------------
__global__ void sniff_dtype(const unsigned* __restrict__ X, int* __restrict__ flag) {
  __shared__ int cnt;
  if (threadIdx.x == 0) cnt = 0;
  __syncthreads();
  unsigned w = X[(size_t)threadIdx.x * 16384 + 1000];
  int e = (int)((w >> 7) & 0xFF);
  if (e >= 100 && e <= 150) atomicAdd(&cnt, 1);
  __syncthreads();
  if (threadIdx.x == 0) flag[0] = (cnt < 192) ? 1 : 0;
}

// ---------------------------------------------------------------------------
// X ingest -> bf16.
// ---------------------------------------------------------------------------
__global__ __launch_bounds__(256) void convert_x(
    const void* __restrict__ X, u16* __restrict__ dst, const int* __restrict__ flag) {
  const int mode = flag[0];
  size_t i8 = ((size_t)blockIdx.x * 256 + threadIdx.x) * 8;
  if (mode) {
    const float4* f = (const float4*)X;
    float4 a = f[i8 / 4], b = f[i8 / 4 + 1];
    u16x8 o;
    o[0] = f2bf(a.x); o[1] = f2bf(a.y); o[2] = f2bf(a.z); o[3] = f2bf(a.w);
    o[4] = f2bf(b.x); o[5] = f2bf(b.y); o[6] = f2bf(b.z); o[7] = f2bf(b.w);
    *(u16x8*)&dst[i8] = o;
  } else {
    *(u16x8*)&dst[i8] = *(const u16x8*)&((const u16*)X)[i8];
  }
}

// ---------------------------------------------------------------------------
// Weight transpose + convert: Wt[n][k] = bf16(W[k][n]), 2048x2048.
// ---------------------------------------------------------------------------
__global__ __launch_bounds__(256) void transpose_w(
    const void* __restrict__ src, u16* __restrict__ d, const int* __restrict__ flag)
{
  __shared__ u16 t[64][65];
  const int mode = flag[0];
  int r0 = blockIdx.y * 64, c0 = blockIdx.x * 64;
  int tid = threadIdx.x;
  for (int j = 0; j < 2; ++j) {
    int idx = tid + j * 256;
    int r = idx >> 3, c = (idx & 7) * 8;
    size_t base = (size_t)(r0 + r) * 2048 + c0 + c;
    if (mode) {
      const float4* f = (const float4*)src;
      float4 a = f[base / 4], b = f[base / 4 + 1];
      t[r][c + 0] = f2bf(a.x); t[r][c + 1] = f2bf(a.y);
      t[r][c + 2] = f2bf(a.z); t[r][c + 3] = f2bf(a.w);
      t[r][c + 4] = f2bf(b.x); t[r][c + 5] = f2bf(b.y);
      t[r][c + 6] = f2bf(b.z); t[r][c + 7] = f2bf(b.w);
    } else {
      u16x8 v = *(const u16x8*)&((const u16*)src)[base];
      for (int q = 0; q < 8; ++q) t[r][c + q] = v[q];
    }
  }
  __syncthreads();
  for (int j = 0; j < 2; ++j) {
    int idx = tid + j * 256;
    int c = idx >> 3, r = (idx & 7) * 8;
    u16x8 v;
    for (int q = 0; q < 8; ++q) v[q] = t[r + q][c];
    *(u16x8*)&d[(size_t)(c0 + c) * 2048 + r0 + r] = v;
  }
}

// ---------------------------------------------------------------------------
// V transpose: Vt[(b*16+h)][d][kv] = V[b*2048+kv][h*128+d]
// ---------------------------------------------------------------------------
__global__ __launch_bounds__(256) void transpose_v(
    const u16* __restrict__ V, u16* __restrict__ Vt)
{
  __shared__ u16 t[64][65];
  int bh = blockIdx.z;
  int b = bh >> 4, h = bh & 15;
  int kv0 = blockIdx.x * 64, d0 = blockIdx.y * 64;
  int tid = threadIdx.x;
  for (int j = 0; j < 2; ++j) {
    int idx = tid + j * 256;
    int r = idx >> 3, c = (idx & 7) * 8;
    u16x8 v = *(const u16x8*)&V[(size_t)(b * 2048 + kv0 + r) * 2048 + h * 128 + d0 + c];
    for (int q = 0; q < 8; ++q) t[r][c + q] = v[q];
  }
  __syncthreads();
  for (int j = 0; j < 2; ++j) {
    int idx = tid + j * 256;
    int c = idx >> 3, r = (idx & 7) * 8;
    u16x8 v;
    for (int q = 0; q < 8; ++q) v[q] = t[r + q][c];
    *(u16x8*)&Vt[((size_t)bh * 128 + d0 + c) * 2048 + kv0 + r] = v;
  }
}

// ---------------------------------------------------------------------------
// RoPE in-place on Q and K (bf16). pos = token % 2048. Precise sincosf.
// ---------------------------------------------------------------------------
__global__ __launch_bounds__(256) void rope_k(u16* __restrict__ Qp, u16* __restrict__ Kp)
{
  int idx = blockIdx.x * 256 + threadIdx.x;
  u16* X = blockIdx.y ? Kp : Qp;
  int i8 = (idx & 7) * 8;
  int h = (idx >> 3) & 15;
  int tok = idx >> 7;
  int pos = tok & 2047;
  size_t base = (size_t)tok * 2048 + h * 128 + i8;
  u16x8 a = *(const u16x8*)&X[base];
  u16x8 bv = *(const u16x8*)&X[base + 64];
  u16x8 ra, rb;
  for (int j = 0; j < 8; ++j) {
    float fi = (float)(i8 + j);
    float invf = __expf(fi * -0.14391156831212787f);  // ln(10000)/64
    float th = (float)pos * invf;
    float c, s;
    sincosf(th, &s, &c);
    float x1 = bf2f(a[j]), x2 = bf2f(bv[j]);
    ra[j] = f2bf(x1 * c - x2 * s);
    rb[j] = f2bf(x2 * c + x1 * s);
  }
  *(u16x8*)&X[base] = ra;
  *(u16x8*)&X[base + 64] = rb;
}

// ---------------------------------------------------------------------------
// GEMM: C[m][n] = sum_k A[m][k]*Bt[n][k]. 128x128 tile, BK=32, 4 waves.
// ROUND-5 DELTA (only change vs round-2 pass): staging via VGPR prefetch +
// ds_write_b128 instead of global_load_lds, to eliminate the 1.8 GB/dispatch
// WRITE_SIZE traffic the DMA path generated. Epilogue unchanged (scalar).
// ---------------------------------------------------------------------------
__global__ __launch_bounds__(256) void gemm_bt(
    const u16* __restrict__ A, const u16* __restrict__ Bt, void* __restrict__ C,
    int M, int N, int K, const int* __restrict__ flag, int dual)
{
  __shared__ __align__(16) u16 As[128 * 32];
  __shared__ __align__(16) u16 Bs[128 * 32];
  const int mode = dual ? flag[0] : 0;
  const int tid = threadIdx.x;
  const int wave = tid >> 6, lane = tid & 63;
  const int quad = lane >> 4, l = lane & 15;
  const int wr = wave >> 1, wc = wave & 1;
  const int m0 = blockIdx.y * 128, n0 = blockIdx.x * 128;

  f32x4 acc[4][4];
  for (int i = 0; i < 4; ++i)
    for (int j = 0; j < 4; ++j) acc[i][j] = zero4();

  int rowA[2], gA[2];
  for (int j = 0; j < 2; ++j) {
    int tf = tid + j * 256;
    rowA[j] = tf >> 2;
    gA[j] = (tf & 3) ^ ((rowA[j] >> 1) & 3);
  }

  u16x8 va[2], vb[2];
  for (int j = 0; j < 2; ++j) {
    va[j] = *(const u16x8*)&A[(size_t)(m0 + rowA[j]) * K + gA[j] * 8];
    vb[j] = *(const u16x8*)&Bt[(size_t)(n0 + rowA[j]) * K + gA[j] * 8];
  }

  for (int kt = 0; kt < K; kt += 32) {
    __syncthreads();                  // prev iter's LDS readers done
    for (int j = 0; j < 2; ++j) {
      int tf = tid + j * 256;
      *(u16x8*)&As[tf * 8] = va[j];
      *(u16x8*)&Bs[tf * 8] = vb[j];
    }
    __syncthreads();
    if (kt + 32 < K) {                // prefetch next tile into VGPRs
      for (int j = 0; j < 2; ++j) {
        va[j] = *(const u16x8*)&A[(size_t)(m0 + rowA[j]) * K + kt + 32 + gA[j] * 8];
        vb[j] = *(const u16x8*)&Bt[(size_t)(n0 + rowA[j]) * K + kt + 32 + gA[j] * 8];
      }
    }
    bf16x8 af[4], bfr[4];
    for (int mt = 0; mt < 4; ++mt) {
      int row = wr * 64 + mt * 16 + l;
      int g = quad ^ ((row >> 1) & 3);
      af[mt] = *(const bf16x8*)&As[row * 32 + g * 8];
    }
    for (int nt = 0; nt < 4; ++nt) {
      int row = wc * 64 + nt * 16 + l;
      int g = quad ^ ((row >> 1) & 3);
      bfr[nt] = *(const bf16x8*)&Bs[row * 32 + g * 8];
    }
    for (int mt = 0; mt < 4; ++mt)
      for (int nt = 0; nt < 4; ++nt)
        acc[mt][nt] = __builtin_amdgcn_mfma_f32_16x16x32_bf16(af[mt], bfr[nt], acc[mt][nt], 0, 0, 0);
  }
  for (int mt = 0; mt < 4; ++mt)
    for (int nt = 0; nt < 4; ++nt)
      for (int r = 0; r < 4; ++r) {
        int m = m0 + wr * 64 + mt * 16 + quad * 4 + r;
        int n = n0 + wc * 64 + nt * 16 + l;
        if (mode) ((float*)C)[(size_t)m * N + n] = acc[mt][nt][r];
        else      ((u16*)C)[(size_t)m * N + n] = f2bf(acc[mt][nt][r]);
      }
}

// ---------------------------------------------------------------------------
// Flash attention, causal — byte-identical to round-2 PASS version.
// grid (32 q-tiles [reversed], 16 h, 2 b). BQ=64, BKV=64, 4 waves x 16 q-rows.
// ---------------------------------------------------------------------------
__global__ __launch_bounds__(256) void flash_k(
    const u16* __restrict__ Q, const u16* __restrict__ K,
    const u16* __restrict__ Vt, u16* __restrict__ O)
{
  __shared__ __align__(16) u16 Qs[64 * 128];
  __shared__ __align__(16) u16 Ks[64 * 128];
  __shared__ __align__(16) u16 Vs[128 * 64];
  __shared__ __align__(16) u16 Ps[4][16 * 64];

  const int tid = threadIdx.x;
  const int wave = tid >> 6, lane = tid & 63;
  const int quad = lane >> 4, l = lane & 15;
  const int qt = (int)gridDim.x - 1 - (int)blockIdx.x;
  const int h = blockIdx.y, b = blockIdx.z;

  const size_t qoff = ((size_t)(b * 2048 + qt * 64)) * 2048 + h * 128;
  for (int j = 0; j < 4; ++j) {
    int tf = tid + j * 256;
    int row = tf >> 4, p = tf & 15;
    int g = p ^ (row & 7);
    async16(&Qs[tf * 8], &Q[qoff + (size_t)row * 2048 + g * 8]);
  }

  f32x4 Oacc[8];
  for (int i = 0; i < 8; ++i) Oacc[i] = zero4();
  float mi[4] = {-3e38f, -3e38f, -3e38f, -3e38f};
  float li[4] = {0.f, 0.f, 0.f, 0.f};

  const size_t kbase = ((size_t)b * 2048) * 2048 + h * 128;
  const size_t vbase = ((size_t)(b * 16 + h)) * 128 * 2048;

  for (int kt = 0; kt <= qt; ++kt) {
    for (int j = 0; j < 4; ++j) {
      int tf = tid + j * 256;
      int row = tf >> 4, p = tf & 15;
      int g = p ^ (row & 7);
      async16(&Ks[tf * 8], &K[kbase + (size_t)(kt * 64 + row) * 2048 + g * 8]);
    }
    for (int j = 0; j < 4; ++j) {
      int tf = tid + j * 256;
      int row = tf >> 3, p = tf & 7;
      int g = p ^ (row & 7);
      async16(&Vs[tf * 8], &Vt[vbase + (size_t)row * 2048 + kt * 64 + g * 8]);
    }
    __syncthreads();

    f32x4 S[4];
    for (int nt = 0; nt < 4; ++nt) S[nt] = zero4();
    for (int ks = 0; ks < 4; ++ks) {
      int g = ks * 4 + quad;
      bf16x8 aq = *(const bf16x8*)&Qs[(wave * 16 + l) * 128 + (g ^ (l & 7)) * 8];
      for (int nt = 0; nt < 4; ++nt) {
        bf16x8 bk = *(const bf16x8*)&Ks[(nt * 16 + l) * 128 + (g ^ (l & 7)) * 8];
        S[nt] = __builtin_amdgcn_mfma_f32_16x16x32_bf16(aq, bk, S[nt], 0, 0, 0);
      }
    }

    const bool dg = (kt == qt);
    float Pv[4][4];
    float rm[4] = {-3e38f, -3e38f, -3e38f, -3e38f};
    for (int nt = 0; nt < 4; ++nt)
      for (int r = 0; r < 4; ++r) {
        float s = S[nt][r] * 0.08838834764831845f;  // 1/sqrt(128)
        if (dg && (nt * 16 + l > wave * 16 + quad * 4 + r)) s = -3e38f;
        Pv[nt][r] = s;
        rm[r] = fmaxf(rm[r], s);
      }
    for (int r = 0; r < 4; ++r)
      for (int off = 1; off < 16; off <<= 1)
        rm[r] = fmaxf(rm[r], __shfl_xor(rm[r], off));
    float al[4], rs[4];
    for (int r = 0; r < 4; ++r) {
      float mn = fmaxf(mi[r], rm[r]);
      al[r] = __expf(mi[r] - mn);
      mi[r] = mn;
      rs[r] = 0.f;
    }
    for (int nt = 0; nt < 4; ++nt)
      for (int r = 0; r < 4; ++r) {
        float p = __expf(Pv[nt][r] - mi[r]);
        Pv[nt][r] = p;
        rs[r] += p;
      }
    for (int r = 0; r < 4; ++r) {
      for (int off = 1; off < 16; off <<= 1)
        rs[r] += __shfl_xor(rs[r], off);
      li[r] = li[r] * al[r] + rs[r];
    }
    for (int nt = 0; nt < 4; ++nt) {
      int gc = nt * 2 + (l >> 3);
      for (int r = 0; r < 4; ++r) {
        int row = quad * 4 + r;
        Ps[wave][row * 64 + ((gc ^ (row & 7)) * 8) + (l & 7)] = f2bf(Pv[nt][r]);
      }
    }
    for (int d = 0; d < 8; ++d)
      for (int r = 0; r < 4; ++r) Oacc[d][r] *= al[r];
    for (int ks = 0; ks < 2; ++ks) {
      int g = ks * 4 + quad;
      bf16x8 ap = *(const bf16x8*)&Ps[wave][l * 64 + (g ^ (l & 7)) * 8];
      for (int d = 0; d < 8; ++d) {
        bf16x8 bv = *(const bf16x8*)&Vs[(d * 16 + l) * 64 + (g ^ (l & 7)) * 8];
        Oacc[d] = __builtin_amdgcn_mfma_f32_16x16x32_bf16(ap, bv, Oacc[d], 0, 0, 0);
      }
    }
    __syncthreads();
  }

  float inv[4];
  for (int r = 0; r < 4; ++r) inv[r] = 1.f / li[r];
  size_t obase = ((size_t)(b * 2048 + qt * 64 + wave * 16)) * 2048 + h * 128;
  for (int d = 0; d < 8; ++d)
    for (int r = 0; r < 4; ++r)
      O[obase + (size_t)(quad * 4 + r) * 2048 + d * 16 + l] = f2bf(Oacc[d][r] * inv[r]);
}

// ---------------------------------------------------------------------------
extern "C" void kernel_launch(void* const* d_in, const int* in_sizes, int n_in,
                              void* d_out, int out_size, void* d_ws, size_t ws_size,
                              hipStream_t stream) {
  const void* X  = d_in[0];
  const void* Wq = d_in[3];
  const void* Wk = d_in[4];
  const void* Wv = d_in[5];
  const void* Wo = d_in[6];

  u16* base = (u16*)d_ws;
  int* flag = (int*)d_ws;
  const size_t TOK = 4096, DM = 2048;
  u16* Xbf = base + 128;
  u16* Qw  = Xbf + TOK * DM;
  u16* Kw  = Qw + TOK * DM;
  u16* Vw  = Kw + TOK * DM;            // V, then attention output
  u16* WTb = Vw + TOK * DM;            // reused per weight
  u16* Vtw = Xbf;                      // X dead after QKV gemms

  sniff_dtype<<<1, 256, 0, stream>>>((const unsigned*)X, flag);
  convert_x<<<4096, 256, 0, stream>>>(X, Xbf, flag);

  transpose_w<<<dim3(32, 32), 256, 0, stream>>>(Wq, WTb, flag);
  gemm_bt<<<dim3(16, 32), 256, 0, stream>>>(Xbf, WTb, Qw, 4096, 2048, 2048, flag, 0);
  transpose_w<<<dim3(32, 32), 256, 0, stream>>>(Wk, WTb, flag);
  gemm_bt<<<dim3(16, 32), 256, 0, stream>>>(Xbf, WTb, Kw, 4096, 2048, 2048, flag, 0);
  transpose_w<<<dim3(32, 32), 256, 0, stream>>>(Wv, WTb, flag);
  gemm_bt<<<dim3(16, 32), 256, 0, stream>>>(Xbf, WTb, Vw, 4096, 2048, 2048, flag, 0);

  rope_k<<<dim3(2048, 2), 256, 0, stream>>>(Qw, Kw);
  transpose_v<<<dim3(32, 2, 32), 256, 0, stream>>>(Vw, Vtw);
  flash_k<<<dim3(32, 16, 2), 256, 0, stream>>>(Qw, Kw, Vtw, Vw);

  transpose_w<<<dim3(32, 32), 256, 0, stream>>>(Wo, WTb, flag);
  gemm_bt<<<dim3(16, 32), 256, 0, stream>>>(Vw, WTb, d_out, 4096, 2048, 2048, flag, 1);
}

// Round 6
// 796.326 us; speedup vs baseline: 2.0074x; 1.9810x over previous
//
#include <hip/hip_runtime.h>
#include <hip/hip_bf16.h>

typedef unsigned short u16;
typedef __bf16 bf16x8 __attribute__((ext_vector_type(8)));
typedef float f32x4 __attribute__((ext_vector_type(4)));
typedef unsigned short u16x8 __attribute__((ext_vector_type(8)));

__device__ __forceinline__ u16 f2bf(float f) {
  union { float f; unsigned u; } v; v.f = f;
  unsigned r = (v.u + 0x7FFFu + ((v.u >> 16) & 1u)) >> 16;
  return (u16)r;
}
__device__ __forceinline__ float bf2f(u16 s) {
  union { unsigned u; float f; } v; v.u = ((unsigned)s) << 16;
  return v.f;
}
__device__ __forceinline__ f32x4 zero4() { f32x4 z = {0.f, 0.f, 0.f, 0.f}; return z; }

__device__ __forceinline__ void async16(void* lds, const void* g) {
  __builtin_amdgcn_global_load_lds(
      (__attribute__((address_space(1))) void*)(void*)g,
      (__attribute__((address_space(3))) void*)lds, 16, 0, 0);
}

// ---------------------------------------------------------------------------
// Dtype sniff: 1 = f32 inputs, 0 = bf16 inputs. Deterministic.
// ---------------------------------------------------------------------------
__global__ void sniff_dtype(const unsigned* __restrict__ X, int* __restrict__ flag) {
  __shared__ int cnt;
  if (threadIdx.x == 0) cnt = 0;
  __syncthreads();
  unsigned w = X[(size_t)threadIdx.x * 16384 + 1000];
  int e = (int)((w >> 7) & 0xFF);
  if (e >= 100 && e <= 150) atomicAdd(&cnt, 1);
  __syncthreads();
  if (threadIdx.x == 0) flag[0] = (cnt < 192) ? 1 : 0;
}

// ---------------------------------------------------------------------------
// X ingest -> bf16.
// ---------------------------------------------------------------------------
__global__ __launch_bounds__(256) void convert_x(
    const void* __restrict__ X, u16* __restrict__ dst, const int* __restrict__ flag) {
  const int mode = flag[0];
  size_t i8 = ((size_t)blockIdx.x * 256 + threadIdx.x) * 8;
  if (mode) {
    const float4* f = (const float4*)X;
    float4 a = f[i8 / 4], b = f[i8 / 4 + 1];
    u16x8 o;
    o[0] = f2bf(a.x); o[1] = f2bf(a.y); o[2] = f2bf(a.z); o[3] = f2bf(a.w);
    o[4] = f2bf(b.x); o[5] = f2bf(b.y); o[6] = f2bf(b.z); o[7] = f2bf(b.w);
    *(u16x8*)&dst[i8] = o;
  } else {
    *(u16x8*)&dst[i8] = *(const u16x8*)&((const u16*)X)[i8];
  }
}

// ---------------------------------------------------------------------------
// Weight transpose + convert: Wt[n][k] = bf16(W[k][n]), 2048x2048.
// ---------------------------------------------------------------------------
__global__ __launch_bounds__(256) void transpose_w(
    const void* __restrict__ src, u16* __restrict__ d, const int* __restrict__ flag)
{
  __shared__ u16 t[64][65];
  const int mode = flag[0];
  int r0 = blockIdx.y * 64, c0 = blockIdx.x * 64;
  int tid = threadIdx.x;
  for (int j = 0; j < 2; ++j) {
    int idx = tid + j * 256;
    int r = idx >> 3, c = (idx & 7) * 8;
    size_t base = (size_t)(r0 + r) * 2048 + c0 + c;
    if (mode) {
      const float4* f = (const float4*)src;
      float4 a = f[base / 4], b = f[base / 4 + 1];
      t[r][c + 0] = f2bf(a.x); t[r][c + 1] = f2bf(a.y);
      t[r][c + 2] = f2bf(a.z); t[r][c + 3] = f2bf(a.w);
      t[r][c + 4] = f2bf(b.x); t[r][c + 5] = f2bf(b.y);
      t[r][c + 6] = f2bf(b.z); t[r][c + 7] = f2bf(b.w);
    } else {
      u16x8 v = *(const u16x8*)&((const u16*)src)[base];
      for (int q = 0; q < 8; ++q) t[r][c + q] = v[q];
    }
  }
  __syncthreads();
  for (int j = 0; j < 2; ++j) {
    int idx = tid + j * 256;
    int c = idx >> 3, r = (idx & 7) * 8;
    u16x8 v;
    for (int q = 0; q < 8; ++q) v[q] = t[r + q][c];
    *(u16x8*)&d[(size_t)(c0 + c) * 2048 + r0 + r] = v;
  }
}

// ---------------------------------------------------------------------------
// V transpose: Vt[(b*16+h)][d][kv] = V[b*2048+kv][h*128+d]
// ---------------------------------------------------------------------------
__global__ __launch_bounds__(256) void transpose_v(
    const u16* __restrict__ V, u16* __restrict__ Vt)
{
  __shared__ u16 t[64][65];
  int bh = blockIdx.z;
  int b = bh >> 4, h = bh & 15;
  int kv0 = blockIdx.x * 64, d0 = blockIdx.y * 64;
  int tid = threadIdx.x;
  for (int j = 0; j < 2; ++j) {
    int idx = tid + j * 256;
    int r = idx >> 3, c = (idx & 7) * 8;
    u16x8 v = *(const u16x8*)&V[(size_t)(b * 2048 + kv0 + r) * 2048 + h * 128 + d0 + c];
    for (int q = 0; q < 8; ++q) t[r][c + q] = v[q];
  }
  __syncthreads();
  for (int j = 0; j < 2; ++j) {
    int idx = tid + j * 256;
    int c = idx >> 3, r = (idx & 7) * 8;
    u16x8 v;
    for (int q = 0; q < 8; ++q) v[q] = t[r + q][c];
    *(u16x8*)&Vt[((size_t)bh * 128 + d0 + c) * 2048 + kv0 + r] = v;
  }
}

// ---------------------------------------------------------------------------
// RoPE in-place on Q and K (bf16). pos = token % 2048. Precise sincosf.
// ---------------------------------------------------------------------------
__global__ __launch_bounds__(256) void rope_k(u16* __restrict__ Qp, u16* __restrict__ Kp)
{
  int idx = blockIdx.x * 256 + threadIdx.x;
  u16* X = blockIdx.y ? Kp : Qp;
  int i8 = (idx & 7) * 8;
  int h = (idx >> 3) & 15;
  int tok = idx >> 7;
  int pos = tok & 2047;
  size_t base = (size_t)tok * 2048 + h * 128 + i8;
  u16x8 a = *(const u16x8*)&X[base];
  u16x8 bv = *(const u16x8*)&X[base + 64];
  u16x8 ra, rb;
  for (int j = 0; j < 8; ++j) {
    float fi = (float)(i8 + j);
    float invf = __expf(fi * -0.14391156831212787f);  // ln(10000)/64
    float th = (float)pos * invf;
    float c, s;
    sincosf(th, &s, &c);
    float x1 = bf2f(a[j]), x2 = bf2f(bv[j]);
    ra[j] = f2bf(x1 * c - x2 * s);
    rb[j] = f2bf(x2 * c + x1 * s);
  }
  *(u16x8*)&X[base] = ra;
  *(u16x8*)&X[base + 64] = rb;
}

// ---------------------------------------------------------------------------
// Fused QKV GEMM: A = Xbf (4096x2048), Bt = WT3 (6144x2048, WqT++WkT++WvT).
// C routed per n-tile to Qw/Kw/Vw (each 4096x2048). Grid (48, 32) = 1536
// blocks = 6 blocks/CU (3x round-5's residency -> tests the overlap theory).
// K-loop/staging/epilogue byte-identical to the passing round-5 gemm_bt.
// ---------------------------------------------------------------------------
__global__ __launch_bounds__(256) void qkv_gemm(
    const u16* __restrict__ A, const u16* __restrict__ Bt,
    u16* __restrict__ Qw, u16* __restrict__ Kw, u16* __restrict__ Vw)
{
  __shared__ __align__(16) u16 As[128 * 32];
  __shared__ __align__(16) u16 Bs[128 * 32];
  const int K = 2048, N = 2048;
  const int tid = threadIdx.x;
  const int wave = tid >> 6, lane = tid & 63;
  const int quad = lane >> 4, l = lane & 15;
  const int wr = wave >> 1, wc = wave & 1;
  const int m0 = blockIdx.y * 128, n0full = blockIdx.x * 128;
  const int mat = n0full >> 11;           // 0=Q, 1=K, 2=V (tile never straddles)
  const int n0 = n0full & 2047;
  u16* C = (mat == 0) ? Qw : ((mat == 1) ? Kw : Vw);

  f32x4 acc[4][4];
  for (int i = 0; i < 4; ++i)
    for (int j = 0; j < 4; ++j) acc[i][j] = zero4();

  int rowA[2], gA[2];
  for (int j = 0; j < 2; ++j) {
    int tf = tid + j * 256;
    rowA[j] = tf >> 2;
    gA[j] = (tf & 3) ^ ((rowA[j] >> 1) & 3);
  }

  u16x8 va[2], vb[2];
  for (int j = 0; j < 2; ++j) {
    va[j] = *(const u16x8*)&A[(size_t)(m0 + rowA[j]) * K + gA[j] * 8];
    vb[j] = *(const u16x8*)&Bt[(size_t)(n0full + rowA[j]) * K + gA[j] * 8];
  }

  for (int kt = 0; kt < K; kt += 32) {
    __syncthreads();
    for (int j = 0; j < 2; ++j) {
      int tf = tid + j * 256;
      *(u16x8*)&As[tf * 8] = va[j];
      *(u16x8*)&Bs[tf * 8] = vb[j];
    }
    __syncthreads();
    if (kt + 32 < K) {
      for (int j = 0; j < 2; ++j) {
        va[j] = *(const u16x8*)&A[(size_t)(m0 + rowA[j]) * K + kt + 32 + gA[j] * 8];
        vb[j] = *(const u16x8*)&Bt[(size_t)(n0full + rowA[j]) * K + kt + 32 + gA[j] * 8];
      }
    }
    bf16x8 af[4], bfr[4];
    for (int mt = 0; mt < 4; ++mt) {
      int row = wr * 64 + mt * 16 + l;
      int g = quad ^ ((row >> 1) & 3);
      af[mt] = *(const bf16x8*)&As[row * 32 + g * 8];
    }
    for (int nt = 0; nt < 4; ++nt) {
      int row = wc * 64 + nt * 16 + l;
      int g = quad ^ ((row >> 1) & 3);
      bfr[nt] = *(const bf16x8*)&Bs[row * 32 + g * 8];
    }
    for (int mt = 0; mt < 4; ++mt)
      for (int nt = 0; nt < 4; ++nt)
        acc[mt][nt] = __builtin_amdgcn_mfma_f32_16x16x32_bf16(af[mt], bfr[nt], acc[mt][nt], 0, 0, 0);
  }
  for (int mt = 0; mt < 4; ++mt)
    for (int nt = 0; nt < 4; ++nt)
      for (int r = 0; r < 4; ++r) {
        int m = m0 + wr * 64 + mt * 16 + quad * 4 + r;
        int n = n0 + wc * 64 + nt * 16 + l;
        C[(size_t)m * N + n] = f2bf(acc[mt][nt][r]);
      }
}

// ---------------------------------------------------------------------------
// GEMM (Wo path, CONTROL — unchanged from round-5 pass).
// ---------------------------------------------------------------------------
__global__ __launch_bounds__(256) void gemm_bt(
    const u16* __restrict__ A, const u16* __restrict__ Bt, void* __restrict__ C,
    int M, int N, int K, const int* __restrict__ flag, int dual)
{
  __shared__ __align__(16) u16 As[128 * 32];
  __shared__ __align__(16) u16 Bs[128 * 32];
  const int mode = dual ? flag[0] : 0;
  const int tid = threadIdx.x;
  const int wave = tid >> 6, lane = tid & 63;
  const int quad = lane >> 4, l = lane & 15;
  const int wr = wave >> 1, wc = wave & 1;
  const int m0 = blockIdx.y * 128, n0 = blockIdx.x * 128;

  f32x4 acc[4][4];
  for (int i = 0; i < 4; ++i)
    for (int j = 0; j < 4; ++j) acc[i][j] = zero4();

  int rowA[2], gA[2];
  for (int j = 0; j < 2; ++j) {
    int tf = tid + j * 256;
    rowA[j] = tf >> 2;
    gA[j] = (tf & 3) ^ ((rowA[j] >> 1) & 3);
  }

  u16x8 va[2], vb[2];
  for (int j = 0; j < 2; ++j) {
    va[j] = *(const u16x8*)&A[(size_t)(m0 + rowA[j]) * K + gA[j] * 8];
    vb[j] = *(const u16x8*)&Bt[(size_t)(n0 + rowA[j]) * K + gA[j] * 8];
  }

  for (int kt = 0; kt < K; kt += 32) {
    __syncthreads();
    for (int j = 0; j < 2; ++j) {
      int tf = tid + j * 256;
      *(u16x8*)&As[tf * 8] = va[j];
      *(u16x8*)&Bs[tf * 8] = vb[j];
    }
    __syncthreads();
    if (kt + 32 < K) {
      for (int j = 0; j < 2; ++j) {
        va[j] = *(const u16x8*)&A[(size_t)(m0 + rowA[j]) * K + kt + 32 + gA[j] * 8];
        vb[j] = *(const u16x8*)&Bt[(size_t)(n0 + rowA[j]) * K + kt + 32 + gA[j] * 8];
      }
    }
    bf16x8 af[4], bfr[4];
    for (int mt = 0; mt < 4; ++mt) {
      int row = wr * 64 + mt * 16 + l;
      int g = quad ^ ((row >> 1) & 3);
      af[mt] = *(const bf16x8*)&As[row * 32 + g * 8];
    }
    for (int nt = 0; nt < 4; ++nt) {
      int row = wc * 64 + nt * 16 + l;
      int g = quad ^ ((row >> 1) & 3);
      bfr[nt] = *(const bf16x8*)&Bs[row * 32 + g * 8];
    }
    for (int mt = 0; mt < 4; ++mt)
      for (int nt = 0; nt < 4; ++nt)
        acc[mt][nt] = __builtin_amdgcn_mfma_f32_16x16x32_bf16(af[mt], bfr[nt], acc[mt][nt], 0, 0, 0);
  }
  for (int mt = 0; mt < 4; ++mt)
    for (int nt = 0; nt < 4; ++nt)
      for (int r = 0; r < 4; ++r) {
        int m = m0 + wr * 64 + mt * 16 + quad * 4 + r;
        int n = n0 + wc * 64 + nt * 16 + l;
        if (mode) ((float*)C)[(size_t)m * N + n] = acc[mt][nt][r];
        else      ((u16*)C)[(size_t)m * N + n] = f2bf(acc[mt][nt][r]);
      }
}

// ---------------------------------------------------------------------------
// Flash attention, causal — unchanged from round-5 pass.
// ---------------------------------------------------------------------------
__global__ __launch_bounds__(256) void flash_k(
    const u16* __restrict__ Q, const u16* __restrict__ K,
    const u16* __restrict__ Vt, u16* __restrict__ O)
{
  __shared__ __align__(16) u16 Qs[64 * 128];
  __shared__ __align__(16) u16 Ks[64 * 128];
  __shared__ __align__(16) u16 Vs[128 * 64];
  __shared__ __align__(16) u16 Ps[4][16 * 64];

  const int tid = threadIdx.x;
  const int wave = tid >> 6, lane = tid & 63;
  const int quad = lane >> 4, l = lane & 15;
  const int qt = (int)gridDim.x - 1 - (int)blockIdx.x;
  const int h = blockIdx.y, b = blockIdx.z;

  const size_t qoff = ((size_t)(b * 2048 + qt * 64)) * 2048 + h * 128;
  for (int j = 0; j < 4; ++j) {
    int tf = tid + j * 256;
    int row = tf >> 4, p = tf & 15;
    int g = p ^ (row & 7);
    async16(&Qs[tf * 8], &Q[qoff + (size_t)row * 2048 + g * 8]);
  }

  f32x4 Oacc[8];
  for (int i = 0; i < 8; ++i) Oacc[i] = zero4();
  float mi[4] = {-3e38f, -3e38f, -3e38f, -3e38f};
  float li[4] = {0.f, 0.f, 0.f, 0.f};

  const size_t kbase = ((size_t)b * 2048) * 2048 + h * 128;
  const size_t vbase = ((size_t)(b * 16 + h)) * 128 * 2048;

  for (int kt = 0; kt <= qt; ++kt) {
    for (int j = 0; j < 4; ++j) {
      int tf = tid + j * 256;
      int row = tf >> 4, p = tf & 15;
      int g = p ^ (row & 7);
      async16(&Ks[tf * 8], &K[kbase + (size_t)(kt * 64 + row) * 2048 + g * 8]);
    }
    for (int j = 0; j < 4; ++j) {
      int tf = tid + j * 256;
      int row = tf >> 3, p = tf & 7;
      int g = p ^ (row & 7);
      async16(&Vs[tf * 8], &Vt[vbase + (size_t)row * 2048 + kt * 64 + g * 8]);
    }
    __syncthreads();

    f32x4 S[4];
    for (int nt = 0; nt < 4; ++nt) S[nt] = zero4();
    for (int ks = 0; ks < 4; ++ks) {
      int g = ks * 4 + quad;
      bf16x8 aq = *(const bf16x8*)&Qs[(wave * 16 + l) * 128 + (g ^ (l & 7)) * 8];
      for (int nt = 0; nt < 4; ++nt) {
        bf16x8 bk = *(const bf16x8*)&Ks[(nt * 16 + l) * 128 + (g ^ (l & 7)) * 8];
        S[nt] = __builtin_amdgcn_mfma_f32_16x16x32_bf16(aq, bk, S[nt], 0, 0, 0);
      }
    }

    const bool dg = (kt == qt);
    float Pv[4][4];
    float rm[4] = {-3e38f, -3e38f, -3e38f, -3e38f};
    for (int nt = 0; nt < 4; ++nt)
      for (int r = 0; r < 4; ++r) {
        float s = S[nt][r] * 0.08838834764831845f;  // 1/sqrt(128)
        if (dg && (nt * 16 + l > wave * 16 + quad * 4 + r)) s = -3e38f;
        Pv[nt][r] = s;
        rm[r] = fmaxf(rm[r], s);
      }
    for (int r = 0; r < 4; ++r)
      for (int off = 1; off < 16; off <<= 1)
        rm[r] = fmaxf(rm[r], __shfl_xor(rm[r], off));
    float al[4], rs[4];
    for (int r = 0; r < 4; ++r) {
      float mn = fmaxf(mi[r], rm[r]);
      al[r] = __expf(mi[r] - mn);
      mi[r] = mn;
      rs[r] = 0.f;
    }
    for (int nt = 0; nt < 4; ++nt)
      for (int r = 0; r < 4; ++r) {
        float p = __expf(Pv[nt][r] - mi[r]);
        Pv[nt][r] = p;
        rs[r] += p;
      }
    for (int r = 0; r < 4; ++r) {
      for (int off = 1; off < 16; off <<= 1)
        rs[r] += __shfl_xor(rs[r], off);
      li[r] = li[r] * al[r] + rs[r];
    }
    for (int nt = 0; nt < 4; ++nt) {
      int gc = nt * 2 + (l >> 3);
      for (int r = 0; r < 4; ++r) {
        int row = quad * 4 + r;
        Ps[wave][row * 64 + ((gc ^ (row & 7)) * 8) + (l & 7)] = f2bf(Pv[nt][r]);
      }
    }
    for (int d = 0; d < 8; ++d)
      for (int r = 0; r < 4; ++r) Oacc[d][r] *= al[r];
    for (int ks = 0; ks < 2; ++ks) {
      int g = ks * 4 + quad;
      bf16x8 ap = *(const bf16x8*)&Ps[wave][l * 64 + (g ^ (l & 7)) * 8];
      for (int d = 0; d < 8; ++d) {
        bf16x8 bv = *(const bf16x8*)&Vs[(d * 16 + l) * 64 + (g ^ (l & 7)) * 8];
        Oacc[d] = __builtin_amdgcn_mfma_f32_16x16x32_bf16(ap, bv, Oacc[d], 0, 0, 0);
      }
    }
    __syncthreads();
  }

  float inv[4];
  for (int r = 0; r < 4; ++r) inv[r] = 1.f / li[r];
  size_t obase = ((size_t)(b * 2048 + qt * 64 + wave * 16)) * 2048 + h * 128;
  for (int d = 0; d < 8; ++d)
    for (int r = 0; r < 4; ++r)
      O[obase + (size_t)(quad * 4 + r) * 2048 + d * 16 + l] = f2bf(Oacc[d][r] * inv[r]);
}

// ---------------------------------------------------------------------------
extern "C" void kernel_launch(void* const* d_in, const int* in_sizes, int n_in,
                              void* d_out, int out_size, void* d_ws, size_t ws_size,
                              hipStream_t stream) {
  const void* X  = d_in[0];
  const void* Wq = d_in[3];
  const void* Wk = d_in[4];
  const void* Wv = d_in[5];
  const void* Wo = d_in[6];

  u16* base = (u16*)d_ws;
  int* flag = (int*)d_ws;
  const size_t TOK = 4096, DM = 2048;
  u16* Xbf = base + 128;               // 8M u16
  u16* Qw  = Xbf + TOK * DM;           // 8M
  u16* Kw  = Qw + TOK * DM;            // 8M
  u16* Vw  = Kw + TOK * DM;            // 8M (V, then attention output)
  u16* WT3 = Vw + TOK * DM;            // 12M u16: WqT ++ WkT ++ WvT (6144x2048)
  u16* Vtw = Xbf;                      // X dead after QKV gemm

  sniff_dtype<<<1, 256, 0, stream>>>((const unsigned*)X, flag);
  convert_x<<<4096, 256, 0, stream>>>(X, Xbf, flag);

  transpose_w<<<dim3(32, 32), 256, 0, stream>>>(Wq, WT3, flag);
  transpose_w<<<dim3(32, 32), 256, 0, stream>>>(Wk, WT3 + DM * DM, flag);
  transpose_w<<<dim3(32, 32), 256, 0, stream>>>(Wv, WT3 + 2 * DM * DM, flag);
  qkv_gemm<<<dim3(48, 32), 256, 0, stream>>>(Xbf, WT3, Qw, Kw, Vw);

  rope_k<<<dim3(2048, 2), 256, 0, stream>>>(Qw, Kw);
  transpose_v<<<dim3(32, 2, 32), 256, 0, stream>>>(Vw, Vtw);
  flash_k<<<dim3(32, 16, 2), 256, 0, stream>>>(Qw, Kw, Vtw, Vw);

  transpose_w<<<dim3(32, 32), 256, 0, stream>>>(Wo, WT3, flag);
  gemm_bt<<<dim3(16, 32), 256, 0, stream>>>(Vw, WT3, d_out, 4096, 2048, 2048, flag, 1);
}

// Round 7
// 577.436 us; speedup vs baseline: 2.7684x; 1.3791x over previous
//
#include <hip/hip_runtime.h>
#include <hip/hip_bf16.h>

typedef unsigned short u16;
typedef __bf16 bf16x8 __attribute__((ext_vector_type(8)));
typedef float f32x4 __attribute__((ext_vector_type(4)));
typedef unsigned short u16x8 __attribute__((ext_vector_type(8)));

__device__ __forceinline__ u16 f2bf(float f) {
  union { float f; unsigned u; } v; v.f = f;
  unsigned r = (v.u + 0x7FFFu + ((v.u >> 16) & 1u)) >> 16;
  return (u16)r;
}
__device__ __forceinline__ float bf2f(u16 s) {
  union { unsigned u; float f; } v; v.u = ((unsigned)s) << 16;
  return v.f;
}
__device__ __forceinline__ f32x4 zero4() { f32x4 z = {0.f, 0.f, 0.f, 0.f}; return z; }

__device__ __forceinline__ void async16(void* lds, const void* g) {
  __builtin_amdgcn_global_load_lds(
      (__attribute__((address_space(1))) void*)(void*)g,
      (__attribute__((address_space(3))) void*)lds, 16, 0, 0);
}

// ---------------------------------------------------------------------------
// Dtype sniff: 1 = f32 inputs, 0 = bf16 inputs. Deterministic.
// ---------------------------------------------------------------------------
__global__ void sniff_dtype(const unsigned* __restrict__ X, int* __restrict__ flag) {
  __shared__ int cnt;
  if (threadIdx.x == 0) cnt = 0;
  __syncthreads();
  unsigned w = X[(size_t)threadIdx.x * 16384 + 1000];
  int e = (int)((w >> 7) & 0xFF);
  if (e >= 100 && e <= 150) atomicAdd(&cnt, 1);
  __syncthreads();
  if (threadIdx.x == 0) flag[0] = (cnt < 192) ? 1 : 0;
}

// ---------------------------------------------------------------------------
// X ingest -> bf16.
// ---------------------------------------------------------------------------
__global__ __launch_bounds__(256) void convert_x(
    const void* __restrict__ X, u16* __restrict__ dst, const int* __restrict__ flag) {
  const int mode = flag[0];
  size_t i8 = ((size_t)blockIdx.x * 256 + threadIdx.x) * 8;
  if (mode) {
    const float4* f = (const float4*)X;
    float4 a = f[i8 / 4], b = f[i8 / 4 + 1];
    u16x8 o;
    o[0] = f2bf(a.x); o[1] = f2bf(a.y); o[2] = f2bf(a.z); o[3] = f2bf(a.w);
    o[4] = f2bf(b.x); o[5] = f2bf(b.y); o[6] = f2bf(b.z); o[7] = f2bf(b.w);
    *(u16x8*)&dst[i8] = o;
  } else {
    *(u16x8*)&dst[i8] = *(const u16x8*)&((const u16*)X)[i8];
  }
}

// ---------------------------------------------------------------------------
// Weight transpose + convert: Wt[n][k] = bf16(W[k][n]), 2048x2048.
// ---------------------------------------------------------------------------
__global__ __launch_bounds__(256) void transpose_w(
    const void* __restrict__ src, u16* __restrict__ d, const int* __restrict__ flag)
{
  __shared__ u16 t[64][65];
  const int mode = flag[0];
  int r0 = blockIdx.y * 64, c0 = blockIdx.x * 64;
  int tid = threadIdx.x;
  for (int j = 0; j < 2; ++j) {
    int idx = tid + j * 256;
    int r = idx >> 3, c = (idx & 7) * 8;
    size_t base = (size_t)(r0 + r) * 2048 + c0 + c;
    if (mode) {
      const float4* f = (const float4*)src;
      float4 a = f[base / 4], b = f[base / 4 + 1];
      t[r][c + 0] = f2bf(a.x); t[r][c + 1] = f2bf(a.y);
      t[r][c + 2] = f2bf(a.z); t[r][c + 3] = f2bf(a.w);
      t[r][c + 4] = f2bf(b.x); t[r][c + 5] = f2bf(b.y);
      t[r][c + 6] = f2bf(b.z); t[r][c + 7] = f2bf(b.w);
    } else {
      u16x8 v = *(const u16x8*)&((const u16*)src)[base];
      for (int q = 0; q < 8; ++q) t[r][c + q] = v[q];
    }
  }
  __syncthreads();
  for (int j = 0; j < 2; ++j) {
    int idx = tid + j * 256;
    int c = idx >> 3, r = (idx & 7) * 8;
    u16x8 v;
    for (int q = 0; q < 8; ++q) v[q] = t[r + q][c];
    *(u16x8*)&d[(size_t)(c0 + c) * 2048 + r0 + r] = v;
  }
}

// ---------------------------------------------------------------------------
// V transpose: Vt[(b*16+h)][d][kv] = V[b*2048+kv][h*128+d]
// ---------------------------------------------------------------------------
__global__ __launch_bounds__(256) void transpose_v(
    const u16* __restrict__ V, u16* __restrict__ Vt)
{
  __shared__ u16 t[64][65];
  int bh = blockIdx.z;
  int b = bh >> 4, h = bh & 15;
  int kv0 = blockIdx.x * 64, d0 = blockIdx.y * 64;
  int tid = threadIdx.x;
  for (int j = 0; j < 2; ++j) {
    int idx = tid + j * 256;
    int r = idx >> 3, c = (idx & 7) * 8;
    u16x8 v = *(const u16x8*)&V[(size_t)(b * 2048 + kv0 + r) * 2048 + h * 128 + d0 + c];
    for (int q = 0; q < 8; ++q) t[r][c + q] = v[q];
  }
  __syncthreads();
  for (int j = 0; j < 2; ++j) {
    int idx = tid + j * 256;
    int c = idx >> 3, r = (idx & 7) * 8;
    u16x8 v;
    for (int q = 0; q < 8; ++q) v[q] = t[r + q][c];
    *(u16x8*)&Vt[((size_t)bh * 128 + d0 + c) * 2048 + kv0 + r] = v;
  }
}

// ---------------------------------------------------------------------------
// RoPE in-place on Q and K (bf16). pos = token % 2048. Precise sincosf.
// ---------------------------------------------------------------------------
__global__ __launch_bounds__(256) void rope_k(u16* __restrict__ Qp, u16* __restrict__ Kp)
{
  int idx = blockIdx.x * 256 + threadIdx.x;
  u16* X = blockIdx.y ? Kp : Qp;
  int i8 = (idx & 7) * 8;
  int h = (idx >> 3) & 15;
  int tok = idx >> 7;
  int pos = tok & 2047;
  size_t base = (size_t)tok * 2048 + h * 128 + i8;
  u16x8 a = *(const u16x8*)&X[base];
  u16x8 bv = *(const u16x8*)&X[base + 64];
  u16x8 ra, rb;
  for (int j = 0; j < 8; ++j) {
    float fi = (float)(i8 + j);
    float invf = __expf(fi * -0.14391156831212787f);  // ln(10000)/64
    float th = (float)pos * invf;
    float c, s;
    sincosf(th, &s, &c);
    float x1 = bf2f(a[j]), x2 = bf2f(bv[j]);
    ra[j] = f2bf(x1 * c - x2 * s);
    rb[j] = f2bf(x2 * c + x1 * s);
  }
  *(u16x8*)&X[base] = ra;
  *(u16x8*)&X[base + 64] = rb;
}

// ---------------------------------------------------------------------------
// Fused QKV GEMM (unchanged from round-6 pass): 128x128 tile, grid (48,32)
// = 1536 blocks = 6 blocks/CU.
// ---------------------------------------------------------------------------
__global__ __launch_bounds__(256) void qkv_gemm(
    const u16* __restrict__ A, const u16* __restrict__ Bt,
    u16* __restrict__ Qw, u16* __restrict__ Kw, u16* __restrict__ Vw)
{
  __shared__ __align__(16) u16 As[128 * 32];
  __shared__ __align__(16) u16 Bs[128 * 32];
  const int K = 2048, N = 2048;
  const int tid = threadIdx.x;
  const int wave = tid >> 6, lane = tid & 63;
  const int quad = lane >> 4, l = lane & 15;
  const int wr = wave >> 1, wc = wave & 1;
  const int m0 = blockIdx.y * 128, n0full = blockIdx.x * 128;
  const int mat = n0full >> 11;
  const int n0 = n0full & 2047;
  u16* C = (mat == 0) ? Qw : ((mat == 1) ? Kw : Vw);

  f32x4 acc[4][4];
  for (int i = 0; i < 4; ++i)
    for (int j = 0; j < 4; ++j) acc[i][j] = zero4();

  int rowA[2], gA[2];
  for (int j = 0; j < 2; ++j) {
    int tf = tid + j * 256;
    rowA[j] = tf >> 2;
    gA[j] = (tf & 3) ^ ((rowA[j] >> 1) & 3);
  }

  u16x8 va[2], vb[2];
  for (int j = 0; j < 2; ++j) {
    va[j] = *(const u16x8*)&A[(size_t)(m0 + rowA[j]) * K + gA[j] * 8];
    vb[j] = *(const u16x8*)&Bt[(size_t)(n0full + rowA[j]) * K + gA[j] * 8];
  }

  for (int kt = 0; kt < K; kt += 32) {
    __syncthreads();
    for (int j = 0; j < 2; ++j) {
      int tf = tid + j * 256;
      *(u16x8*)&As[tf * 8] = va[j];
      *(u16x8*)&Bs[tf * 8] = vb[j];
    }
    __syncthreads();
    if (kt + 32 < K) {
      for (int j = 0; j < 2; ++j) {
        va[j] = *(const u16x8*)&A[(size_t)(m0 + rowA[j]) * K + kt + 32 + gA[j] * 8];
        vb[j] = *(const u16x8*)&Bt[(size_t)(n0full + rowA[j]) * K + kt + 32 + gA[j] * 8];
      }
    }
    bf16x8 af[4], bfr[4];
    for (int mt = 0; mt < 4; ++mt) {
      int row = wr * 64 + mt * 16 + l;
      int g = quad ^ ((row >> 1) & 3);
      af[mt] = *(const bf16x8*)&As[row * 32 + g * 8];
    }
    for (int nt = 0; nt < 4; ++nt) {
      int row = wc * 64 + nt * 16 + l;
      int g = quad ^ ((row >> 1) & 3);
      bfr[nt] = *(const bf16x8*)&Bs[row * 32 + g * 8];
    }
    for (int mt = 0; mt < 4; ++mt)
      for (int nt = 0; nt < 4; ++nt)
        acc[mt][nt] = __builtin_amdgcn_mfma_f32_16x16x32_bf16(af[mt], bfr[nt], acc[mt][nt], 0, 0, 0);
  }
  for (int mt = 0; mt < 4; ++mt)
    for (int nt = 0; nt < 4; ++nt)
      for (int r = 0; r < 4; ++r) {
        int m = m0 + wr * 64 + mt * 16 + quad * 4 + r;
        int n = n0 + wc * 64 + nt * 16 + l;
        C[(size_t)m * N + n] = f2bf(acc[mt][nt][r]);
      }
}

// ---------------------------------------------------------------------------
// Wo GEMM, ROUND-7 DELTA: 64x64 tile -> grid (N/64=32, M/64=64) = 2048 blocks
// = 8 blocks/CU (vs 2 at 128x128). Same staging algebra / VGPR prefetch /
// scalar dual-mode epilogue as the round-5/6 passing gemm. 4 waves in 2x2,
// acc[2][2] per wave. LDS 8 KB.
// ---------------------------------------------------------------------------
__global__ __launch_bounds__(256) void gemm64_bt(
    const u16* __restrict__ A, const u16* __restrict__ Bt, void* __restrict__ C,
    int M, int N, int K, const int* __restrict__ flag, int dual)
{
  __shared__ __align__(16) u16 As[64 * 32];
  __shared__ __align__(16) u16 Bs[64 * 32];
  const int mode = dual ? flag[0] : 0;
  const int tid = threadIdx.x;
  const int wave = tid >> 6, lane = tid & 63;
  const int quad = lane >> 4, l = lane & 15;
  const int wr = wave >> 1, wc = wave & 1;
  const int m0 = blockIdx.y * 64, n0 = blockIdx.x * 64;

  f32x4 acc[2][2];
  for (int i = 0; i < 2; ++i)
    for (int j = 0; j < 2; ++j) acc[i][j] = zero4();

  // 64x32 tile = 2048 u16 = 256 slots of 8: exactly one slot/thread per matrix
  const int rowA = tid >> 2;
  const int gA = (tid & 3) ^ ((rowA >> 1) & 3);

  u16x8 va = *(const u16x8*)&A[(size_t)(m0 + rowA) * K + gA * 8];
  u16x8 vb = *(const u16x8*)&Bt[(size_t)(n0 + rowA) * K + gA * 8];

  for (int kt = 0; kt < K; kt += 32) {
    __syncthreads();                  // prev iter's LDS readers done
    *(u16x8*)&As[tid * 8] = va;
    *(u16x8*)&Bs[tid * 8] = vb;
    __syncthreads();
    if (kt + 32 < K) {                // prefetch next tile into VGPRs
      va = *(const u16x8*)&A[(size_t)(m0 + rowA) * K + kt + 32 + gA * 8];
      vb = *(const u16x8*)&Bt[(size_t)(n0 + rowA) * K + kt + 32 + gA * 8];
    }
    bf16x8 af[2], bfr[2];
    for (int mt = 0; mt < 2; ++mt) {
      int row = wr * 32 + mt * 16 + l;
      int g = quad ^ ((row >> 1) & 3);
      af[mt] = *(const bf16x8*)&As[row * 32 + g * 8];
    }
    for (int nt = 0; nt < 2; ++nt) {
      int row = wc * 32 + nt * 16 + l;
      int g = quad ^ ((row >> 1) & 3);
      bfr[nt] = *(const bf16x8*)&Bs[row * 32 + g * 8];
    }
    for (int mt = 0; mt < 2; ++mt)
      for (int nt = 0; nt < 2; ++nt)
        acc[mt][nt] = __builtin_amdgcn_mfma_f32_16x16x32_bf16(af[mt], bfr[nt], acc[mt][nt], 0, 0, 0);
  }
  for (int mt = 0; mt < 2; ++mt)
    for (int nt = 0; nt < 2; ++nt)
      for (int r = 0; r < 4; ++r) {
        int m = m0 + wr * 32 + mt * 16 + quad * 4 + r;
        int n = n0 + wc * 32 + nt * 16 + l;
        if (mode) ((float*)C)[(size_t)m * N + n] = acc[mt][nt][r];
        else      ((u16*)C)[(size_t)m * N + n] = f2bf(acc[mt][nt][r]);
      }
}

// ---------------------------------------------------------------------------
// Flash attention, causal — unchanged from round-5/6 pass.
// ---------------------------------------------------------------------------
__global__ __launch_bounds__(256) void flash_k(
    const u16* __restrict__ Q, const u16* __restrict__ K,
    const u16* __restrict__ Vt, u16* __restrict__ O)
{
  __shared__ __align__(16) u16 Qs[64 * 128];
  __shared__ __align__(16) u16 Ks[64 * 128];
  __shared__ __align__(16) u16 Vs[128 * 64];
  __shared__ __align__(16) u16 Ps[4][16 * 64];

  const int tid = threadIdx.x;
  const int wave = tid >> 6, lane = tid & 63;
  const int quad = lane >> 4, l = lane & 15;
  const int qt = (int)gridDim.x - 1 - (int)blockIdx.x;
  const int h = blockIdx.y, b = blockIdx.z;

  const size_t qoff = ((size_t)(b * 2048 + qt * 64)) * 2048 + h * 128;
  for (int j = 0; j < 4; ++j) {
    int tf = tid + j * 256;
    int row = tf >> 4, p = tf & 15;
    int g = p ^ (row & 7);
    async16(&Qs[tf * 8], &Q[qoff + (size_t)row * 2048 + g * 8]);
  }

  f32x4 Oacc[8];
  for (int i = 0; i < 8; ++i) Oacc[i] = zero4();
  float mi[4] = {-3e38f, -3e38f, -3e38f, -3e38f};
  float li[4] = {0.f, 0.f, 0.f, 0.f};

  const size_t kbase = ((size_t)b * 2048) * 2048 + h * 128;
  const size_t vbase = ((size_t)(b * 16 + h)) * 128 * 2048;

  for (int kt = 0; kt <= qt; ++kt) {
    for (int j = 0; j < 4; ++j) {
      int tf = tid + j * 256;
      int row = tf >> 4, p = tf & 15;
      int g = p ^ (row & 7);
      async16(&Ks[tf * 8], &K[kbase + (size_t)(kt * 64 + row) * 2048 + g * 8]);
    }
    for (int j = 0; j < 4; ++j) {
      int tf = tid + j * 256;
      int row = tf >> 3, p = tf & 7;
      int g = p ^ (row & 7);
      async16(&Vs[tf * 8], &Vt[vbase + (size_t)row * 2048 + kt * 64 + g * 8]);
    }
    __syncthreads();

    f32x4 S[4];
    for (int nt = 0; nt < 4; ++nt) S[nt] = zero4();
    for (int ks = 0; ks < 4; ++ks) {
      int g = ks * 4 + quad;
      bf16x8 aq = *(const bf16x8*)&Qs[(wave * 16 + l) * 128 + (g ^ (l & 7)) * 8];
      for (int nt = 0; nt < 4; ++nt) {
        bf16x8 bk = *(const bf16x8*)&Ks[(nt * 16 + l) * 128 + (g ^ (l & 7)) * 8];
        S[nt] = __builtin_amdgcn_mfma_f32_16x16x32_bf16(aq, bk, S[nt], 0, 0, 0);
      }
    }

    const bool dg = (kt == qt);
    float Pv[4][4];
    float rm[4] = {-3e38f, -3e38f, -3e38f, -3e38f};
    for (int nt = 0; nt < 4; ++nt)
      for (int r = 0; r < 4; ++r) {
        float s = S[nt][r] * 0.08838834764831845f;  // 1/sqrt(128)
        if (dg && (nt * 16 + l > wave * 16 + quad * 4 + r)) s = -3e38f;
        Pv[nt][r] = s;
        rm[r] = fmaxf(rm[r], s);
      }
    for (int r = 0; r < 4; ++r)
      for (int off = 1; off < 16; off <<= 1)
        rm[r] = fmaxf(rm[r], __shfl_xor(rm[r], off));
    float al[4], rs[4];
    for (int r = 0; r < 4; ++r) {
      float mn = fmaxf(mi[r], rm[r]);
      al[r] = __expf(mi[r] - mn);
      mi[r] = mn;
      rs[r] = 0.f;
    }
    for (int nt = 0; nt < 4; ++nt)
      for (int r = 0; r < 4; ++r) {
        float p = __expf(Pv[nt][r] - mi[r]);
        Pv[nt][r] = p;
        rs[r] += p;
      }
    for (int r = 0; r < 4; ++r) {
      for (int off = 1; off < 16; off <<= 1)
        rs[r] += __shfl_xor(rs[r], off);
      li[r] = li[r] * al[r] + rs[r];
    }
    for (int nt = 0; nt < 4; ++nt) {
      int gc = nt * 2 + (l >> 3);
      for (int r = 0; r < 4; ++r) {
        int row = quad * 4 + r;
        Ps[wave][row * 64 + ((gc ^ (row & 7)) * 8) + (l & 7)] = f2bf(Pv[nt][r]);
      }
    }
    for (int d = 0; d < 8; ++d)
      for (int r = 0; r < 4; ++r) Oacc[d][r] *= al[r];
    for (int ks = 0; ks < 2; ++ks) {
      int g = ks * 4 + quad;
      bf16x8 ap = *(const bf16x8*)&Ps[wave][l * 64 + (g ^ (l & 7)) * 8];
      for (int d = 0; d < 8; ++d) {
        bf16x8 bv = *(const bf16x8*)&Vs[(d * 16 + l) * 64 + (g ^ (l & 7)) * 8];
        Oacc[d] = __builtin_amdgcn_mfma_f32_16x16x32_bf16(ap, bv, Oacc[d], 0, 0, 0);
      }
    }
    __syncthreads();
  }

  float inv[4];
  for (int r = 0; r < 4; ++r) inv[r] = 1.f / li[r];
  size_t obase = ((size_t)(b * 2048 + qt * 64 + wave * 16)) * 2048 + h * 128;
  for (int d = 0; d < 8; ++d)
    for (int r = 0; r < 4; ++r)
      O[obase + (size_t)(quad * 4 + r) * 2048 + d * 16 + l] = f2bf(Oacc[d][r] * inv[r]);
}

// ---------------------------------------------------------------------------
extern "C" void kernel_launch(void* const* d_in, const int* in_sizes, int n_in,
                              void* d_out, int out_size, void* d_ws, size_t ws_size,
                              hipStream_t stream) {
  const void* X  = d_in[0];
  const void* Wq = d_in[3];
  const void* Wk = d_in[4];
  const void* Wv = d_in[5];
  const void* Wo = d_in[6];

  u16* base = (u16*)d_ws;
  int* flag = (int*)d_ws;
  const size_t TOK = 4096, DM = 2048;
  u16* Xbf = base + 128;               // 8M u16
  u16* Qw  = Xbf + TOK * DM;           // 8M
  u16* Kw  = Qw + TOK * DM;            // 8M
  u16* Vw  = Kw + TOK * DM;            // 8M (V, then attention output)
  u16* WT3 = Vw + TOK * DM;            // 12M u16: WqT ++ WkT ++ WvT (6144x2048)
  u16* Vtw = Xbf;                      // X dead after QKV gemm

  sniff_dtype<<<1, 256, 0, stream>>>((const unsigned*)X, flag);
  convert_x<<<4096, 256, 0, stream>>>(X, Xbf, flag);

  transpose_w<<<dim3(32, 32), 256, 0, stream>>>(Wq, WT3, flag);
  transpose_w<<<dim3(32, 32), 256, 0, stream>>>(Wk, WT3 + DM * DM, flag);
  transpose_w<<<dim3(32, 32), 256, 0, stream>>>(Wv, WT3 + 2 * DM * DM, flag);
  qkv_gemm<<<dim3(48, 32), 256, 0, stream>>>(Xbf, WT3, Qw, Kw, Vw);

  rope_k<<<dim3(2048, 2), 256, 0, stream>>>(Qw, Kw);
  transpose_v<<<dim3(32, 2, 32), 256, 0, stream>>>(Vw, Vtw);
  flash_k<<<dim3(32, 16, 2), 256, 0, stream>>>(Qw, Kw, Vtw, Vw);

  transpose_w<<<dim3(32, 32), 256, 0, stream>>>(Wo, WT3, flag);
  gemm64_bt<<<dim3(32, 64), 256, 0, stream>>>(Vw, WT3, d_out, 4096, 2048, 2048, flag, 1);
}